// Round 12
// baseline (2577.949 us; speedup 1.0000x reference)
//
#include <hip/hip_runtime.h>

// EdgeClassifierGNN R12. From R11 profile: linear64_ab was 250us at 9% occ /
// 5% VALU (782 single-wave blocks = no TLP, serialized uniform weight loads);
// edge was 253us at 23.8% occ (17.4KB LDS -> 9 blocks/CU, gather latency
// exposed). Fixes: linears use lane=(node-oct, ch-oct) with y[8] accums,
// 256-thr blocks, 6252 waves, per-co float4 weight loads (L1-hot);
// ab exchanges h3 via padded LDS tile. Edge: two 32-edge batches over an
// 8.7KB tile (18 blocks/CU), 4-edge-unrolled gathers, phase2 lane=(edge,half)
// + 32x shfl_xor combine.

__device__ __forceinline__ void fma8(float (&y)[8], float zv,
                                     const float4& a, const float4& b) {
    y[0] += zv * a.x; y[1] += zv * a.y; y[2] += zv * a.z; y[3] += zv * a.w;
    y[4] += zv * b.x; y[5] += zv * b.y; y[6] += zv * b.z; y[7] += zv * b.w;
}

__global__ __launch_bounds__(256) void hist_kernel(const int* __restrict__ ei, int E,
                                                   int* __restrict__ cnt) {
    int e = blockIdx.x * blockDim.x + threadIdx.x;
    if (e < E) atomicAdd(&cnt[ei[E + e]], 1);
}

__global__ __launch_bounds__(1024) void scan_kernel(const int* __restrict__ cnt,
                                                    int* __restrict__ rowptr, int N) {
    __shared__ int sums[1024];
    int t = threadIdx.x;
    int chunk = (N + 1023) >> 10;
    int start = t * chunk;
    int end = min(start + chunk, N);
    int s = 0;
    for (int i = start; i < end; ++i) s += cnt[i];
    sums[t] = s;
    __syncthreads();
    for (int off = 1; off < 1024; off <<= 1) {
        int v = (t >= off) ? sums[t - off] : 0;
        __syncthreads();
        sums[t] += v;
        __syncthreads();
    }
    int run = (t == 0) ? 0 : sums[t - 1];
    if (t == 0) rowptr[0] = 0;
    for (int i = start; i < end; ++i) { run += cnt[i]; rowptr[i + 1] = run; }
}

__global__ __launch_bounds__(256) void fill_kernel(const int* __restrict__ ei, int E,
                                                   const int* __restrict__ rowptr,
                                                   int* __restrict__ cursor,
                                                   int2* __restrict__ sd,
                                                   int* __restrict__ eid) {
    int e = blockIdx.x * blockDim.x + threadIdx.x;
    if (e >= E) return;
    int s = ei[e], d = ei[E + e];
    int p = rowptr[d] + atomicAdd(&cursor[d], 1);
    sd[p] = make_int2(s, d);
    eid[p] = e;
}

// SAGE layer 1: 16 -> 64. One wave per node; 4 groups of 16 lanes gather rows.
__global__ __launch_bounds__(256) void sage16_kernel(
        const float* __restrict__ x, const int* __restrict__ rowptr,
        const int2* __restrict__ sd, const float* __restrict__ Wl,
        const float* __restrict__ Wr, const float* __restrict__ b,
        float* __restrict__ out, int N) {
    int lane = threadIdx.x & 63;
    int wid  = (blockIdx.x * blockDim.x + threadIdx.x) >> 6;
    if (wid >= N) return;
    int f = lane & 15, g = lane >> 4;
    int s0 = rowptr[wid], s1 = rowptr[wid + 1];
    float acc0 = 0.f, acc1 = 0.f;
    int j = s0 + g;
    for (; j + 4 < s1; j += 8) {
        int c0 = sd[j].x, c1 = sd[j + 4].x;
        acc0 += x[(size_t)c0 * 16 + f];
        acc1 += x[(size_t)c1 * 16 + f];
    }
    if (j < s1) acc0 += x[(size_t)sd[j].x * 16 + f];
    float acc = acc0 + acc1;
    acc += __shfl_xor(acc, 16);
    acc += __shfl_xor(acc, 32);
    float inv  = 1.0f / fmaxf((float)(s1 - s0), 1.0f);
    float mean = acc * inv;
    float xi   = x[(size_t)wid * 16 + f];
    float o = b[lane];
    #pragma unroll
    for (int ff = 0; ff < 16; ++ff) {
        float m  = __shfl(mean, ff);
        float xv = __shfl(xi, ff);
        o += m * Wl[ff * 64 + lane];
        o += xv * Wr[ff * 64 + lane];
    }
    out[(size_t)wid * 64 + lane] = fmaxf(o, 0.f);
}

// Mean aggregation 64-wide: one wave per node, 8 rows in flight, zero DS.
__global__ __launch_bounds__(256) void gather_mean_kernel(
        const float* __restrict__ hin, const int* __restrict__ rowptr,
        const int2* __restrict__ sd, float* __restrict__ m, int N) {
    int lane = threadIdx.x & 63;
    int wid  = (blockIdx.x * blockDim.x + threadIdx.x) >> 6;
    if (wid >= N) return;
    int s0 = rowptr[wid], s1 = rowptr[wid + 1];
    float a0 = 0.f, a1 = 0.f, a2 = 0.f, a3 = 0.f;
    float a4 = 0.f, a5 = 0.f, a6 = 0.f, a7 = 0.f;
    int j = s0;
    for (; j + 8 <= s1; j += 8) {
        int c0 = sd[j].x,     c1 = sd[j + 1].x, c2 = sd[j + 2].x, c3 = sd[j + 3].x;
        int c4 = sd[j + 4].x, c5 = sd[j + 5].x, c6 = sd[j + 6].x, c7 = sd[j + 7].x;
        a0 += hin[(size_t)c0 * 64 + lane];
        a1 += hin[(size_t)c1 * 64 + lane];
        a2 += hin[(size_t)c2 * 64 + lane];
        a3 += hin[(size_t)c3 * 64 + lane];
        a4 += hin[(size_t)c4 * 64 + lane];
        a5 += hin[(size_t)c5 * 64 + lane];
        a6 += hin[(size_t)c6 * 64 + lane];
        a7 += hin[(size_t)c7 * 64 + lane];
    }
    for (; j < s1; ++j) a0 += hin[(size_t)sd[j].x * 64 + lane];
    float s = ((a0 + a1) + (a2 + a3)) + ((a4 + a5) + (a6 + a7));
    m[(size_t)wid * 64 + lane] = s / fmaxf((float)(s1 - s0), 1.0f);
}

// out[i] = relu(m[i]@Wl + h[i]@Wr + b). 256 thr = 4 waves, 32 nodes/block.
// lane = (node-oct ns, ch-oct co): y[8] accum; input z broadcast (8 lanes
// same addr); weights as per-co float4 loads (L1-hot).
__global__ __launch_bounds__(256) void linear64_kernel(
        const float* __restrict__ m, const float* __restrict__ h,
        const float* __restrict__ Wl, const float* __restrict__ Wr,
        const float* __restrict__ b, float* __restrict__ out, int N) {
    int lane = threadIdx.x & 63;
    int wv   = threadIdx.x >> 6;
    int ns   = lane >> 3, co = lane & 7;
    int node = blockIdx.x * 32 + wv * 8 + ns;
    int i    = min(node, N - 1);
    float y[8];
    {
        float4 b0 = *(const float4*)&b[co * 8];
        float4 b1 = *(const float4*)&b[co * 8 + 4];
        y[0] = b0.x; y[1] = b0.y; y[2] = b0.z; y[3] = b0.w;
        y[4] = b1.x; y[5] = b1.y; y[6] = b1.z; y[7] = b1.w;
    }
    const float* mrow = &m[(size_t)i * 64];
    const float* hrow = &h[(size_t)i * 64];
    for (int t = 0; t < 16; ++t) {
        float4 z4 = *(const float4*)&mrow[t * 4];
        #pragma unroll
        for (int j = 0; j < 4; ++j) {
            int ff = t * 4 + j;
            float zv = j == 0 ? z4.x : j == 1 ? z4.y : j == 2 ? z4.z : z4.w;
            float4 wa = *(const float4*)&Wl[ff * 64 + co * 8];
            float4 wb = *(const float4*)&Wl[ff * 64 + co * 8 + 4];
            fma8(y, zv, wa, wb);
        }
    }
    for (int t = 0; t < 16; ++t) {
        float4 z4 = *(const float4*)&hrow[t * 4];
        #pragma unroll
        for (int j = 0; j < 4; ++j) {
            int ff = t * 4 + j;
            float zv = j == 0 ? z4.x : j == 1 ? z4.y : j == 2 ? z4.z : z4.w;
            float4 wa = *(const float4*)&Wr[ff * 64 + co * 8];
            float4 wb = *(const float4*)&Wr[ff * 64 + co * 8 + 4];
            fma8(y, zv, wa, wb);
        }
    }
    if (node < N) {
        float4 o0 = make_float4(fmaxf(y[0], 0.f), fmaxf(y[1], 0.f),
                                fmaxf(y[2], 0.f), fmaxf(y[3], 0.f));
        float4 o1 = make_float4(fmaxf(y[4], 0.f), fmaxf(y[5], 0.f),
                                fmaxf(y[6], 0.f), fmaxf(y[7], 0.f));
        *(float4*)&out[(size_t)node * 64 + co * 8]     = o0;
        *(float4*)&out[(size_t)node * 64 + co * 8 + 4] = o1;
    }
}

// Layer-3 linear fused with A/B precompute. Same lane mapping; h3 exchanged
// through a padded per-wave LDS tile (stride 68 -> conflict-free b128).
__global__ __launch_bounds__(256) void linear64_ab_kernel(
        const float* __restrict__ m, const float* __restrict__ h,
        const float* __restrict__ Wl, const float* __restrict__ Wr,
        const float* __restrict__ b, const float* __restrict__ Wm1,
        const float* __restrict__ bm1, float* __restrict__ A,
        float* __restrict__ Bf, int N) {
    __shared__ float xch[4][8 * 68];
    int lane = threadIdx.x & 63;
    int wv   = threadIdx.x >> 6;
    int ns   = lane >> 3, co = lane & 7;
    int node = blockIdx.x * 32 + wv * 8 + ns;
    int i    = min(node, N - 1);
    float y[8];
    {
        float4 b0 = *(const float4*)&b[co * 8];
        float4 b1 = *(const float4*)&b[co * 8 + 4];
        y[0] = b0.x; y[1] = b0.y; y[2] = b0.z; y[3] = b0.w;
        y[4] = b1.x; y[5] = b1.y; y[6] = b1.z; y[7] = b1.w;
    }
    const float* mrow = &m[(size_t)i * 64];
    const float* hrow = &h[(size_t)i * 64];
    for (int t = 0; t < 16; ++t) {
        float4 z4 = *(const float4*)&mrow[t * 4];
        #pragma unroll
        for (int j = 0; j < 4; ++j) {
            int ff = t * 4 + j;
            float zv = j == 0 ? z4.x : j == 1 ? z4.y : j == 2 ? z4.z : z4.w;
            float4 wa = *(const float4*)&Wl[ff * 64 + co * 8];
            float4 wb = *(const float4*)&Wl[ff * 64 + co * 8 + 4];
            fma8(y, zv, wa, wb);
        }
    }
    for (int t = 0; t < 16; ++t) {
        float4 z4 = *(const float4*)&hrow[t * 4];
        #pragma unroll
        for (int j = 0; j < 4; ++j) {
            int ff = t * 4 + j;
            float zv = j == 0 ? z4.x : j == 1 ? z4.y : j == 2 ? z4.z : z4.w;
            float4 wa = *(const float4*)&Wr[ff * 64 + co * 8];
            float4 wb = *(const float4*)&Wr[ff * 64 + co * 8 + 4];
            fma8(y, zv, wa, wb);
        }
    }
    // h3 = relu(y); exchange so每 lane can read its node's full h3 row.
    {
        float4 h0 = make_float4(fmaxf(y[0], 0.f), fmaxf(y[1], 0.f),
                                fmaxf(y[2], 0.f), fmaxf(y[3], 0.f));
        float4 h1 = make_float4(fmaxf(y[4], 0.f), fmaxf(y[5], 0.f),
                                fmaxf(y[6], 0.f), fmaxf(y[7], 0.f));
        *(float4*)&xch[wv][ns * 68 + co * 8]     = h0;
        *(float4*)&xch[wv][ns * 68 + co * 8 + 4] = h1;
    }
    __syncthreads();
    float yA[8], yB[8];
    {
        float4 b0 = *(const float4*)&bm1[co * 8];
        float4 b1 = *(const float4*)&bm1[co * 8 + 4];
        yA[0] = b0.x; yA[1] = b0.y; yA[2] = b0.z; yA[3] = b0.w;
        yA[4] = b1.x; yA[5] = b1.y; yA[6] = b1.z; yA[7] = b1.w;
        #pragma unroll
        for (int q = 0; q < 8; ++q) yB[q] = 0.f;
    }
    const float* zrow = &xch[wv][ns * 68];
    for (int t = 0; t < 16; ++t) {
        float4 z4 = *(const float4*)&zrow[t * 4];
        #pragma unroll
        for (int j = 0; j < 4; ++j) {
            int ff = t * 4 + j;
            float zv = j == 0 ? z4.x : j == 1 ? z4.y : j == 2 ? z4.z : z4.w;
            float4 wa = *(const float4*)&Wm1[ff * 64 + co * 8];
            float4 wb = *(const float4*)&Wm1[ff * 64 + co * 8 + 4];
            fma8(yA, zv, wa, wb);
            float4 va = *(const float4*)&Wm1[(64 + ff) * 64 + co * 8];
            float4 vb = *(const float4*)&Wm1[(64 + ff) * 64 + co * 8 + 4];
            fma8(yB, zv, va, vb);
        }
    }
    if (node < N) {
        *(float4*)&A[(size_t)node * 64 + co * 8] =
            make_float4(yA[0], yA[1], yA[2], yA[3]);
        *(float4*)&A[(size_t)node * 64 + co * 8 + 4] =
            make_float4(yA[4], yA[5], yA[6], yA[7]);
        *(float4*)&Bf[(size_t)node * 64 + co * 8] =
            make_float4(yB[0], yB[1], yB[2], yB[3]);
        *(float4*)&Bf[(size_t)node * 64 + co * 8 + 4] =
            make_float4(yB[4], yB[5], yB[6], yB[7]);
    }
}

// Edge MLP: 64 edges/block in TWO 32-edge batches over one 8.7KB tile
// (18 blocks/CU). Phase1 (lane=channel, 4-edge unroll): z -> LDS.
// Phase2 lane=(edge, z-half): y[32] partials, shfl_xor(32) combine.
__global__ __launch_bounds__(64) void edge_kernel(
        const float* __restrict__ A, const float* __restrict__ Bf,
        const int2* __restrict__ sd, const int* __restrict__ eid,
        const float* __restrict__ attr,
        const float* __restrict__ Wm1, const float* __restrict__ Wm2,
        const float* __restrict__ bm2, const float* __restrict__ Wm3,
        const float* __restrict__ bm3, float* __restrict__ out, int E) {
    __shared__ float zt[32 * 68];
    int lane = threadIdx.x;
    int base = blockIdx.x * 64;
    float wmE[8];
    #pragma unroll
    for (int k = 0; k < 8; ++k) wmE[k] = Wm1[(128 + k) * 64 + lane];
    const float4* attr4 = (const float4*)attr;
    int eh = lane & 31, hh = lane >> 5;
    float bias3 = bm3[0];

    for (int batch = 0; batch < 2; ++batch) {
        int ebase = base + batch * 32;
        for (int i = 0; i < 32; i += 4) {
            int e0 = ebase + i;
            int ec0 = min(e0,     E - 1), ec1 = min(e0 + 1, E - 1);
            int ec2 = min(e0 + 2, E - 1), ec3 = min(e0 + 3, E - 1);
            int2 p0 = sd[ec0], p1 = sd[ec1], p2 = sd[ec2], p3 = sd[ec3];
            int id0 = eid[ec0], id1 = eid[ec1], id2 = eid[ec2], id3 = eid[ec3];
            float a0 = A[(size_t)p0.x * 64 + lane];
            float a1 = A[(size_t)p1.x * 64 + lane];
            float a2 = A[(size_t)p2.x * 64 + lane];
            float a3 = A[(size_t)p3.x * 64 + lane];
            float v0 = Bf[(size_t)p0.y * 64 + lane];
            float v1 = Bf[(size_t)p1.y * 64 + lane];
            float v2 = Bf[(size_t)p2.y * 64 + lane];
            float v3 = Bf[(size_t)p3.y * 64 + lane];
            float4 q0a = attr4[(size_t)id0 * 2], q0b = attr4[(size_t)id0 * 2 + 1];
            float4 q1a = attr4[(size_t)id1 * 2], q1b = attr4[(size_t)id1 * 2 + 1];
            float4 q2a = attr4[(size_t)id2 * 2], q2b = attr4[(size_t)id2 * 2 + 1];
            float4 q3a = attr4[(size_t)id3 * 2], q3b = attr4[(size_t)id3 * 2 + 1];
            float z0 = a0 + v0 + q0a.x*wmE[0] + q0a.y*wmE[1] + q0a.z*wmE[2] + q0a.w*wmE[3]
                               + q0b.x*wmE[4] + q0b.y*wmE[5] + q0b.z*wmE[6] + q0b.w*wmE[7];
            float z1 = a1 + v1 + q1a.x*wmE[0] + q1a.y*wmE[1] + q1a.z*wmE[2] + q1a.w*wmE[3]
                               + q1b.x*wmE[4] + q1b.y*wmE[5] + q1b.z*wmE[6] + q1b.w*wmE[7];
            float z2 = a2 + v2 + q2a.x*wmE[0] + q2a.y*wmE[1] + q2a.z*wmE[2] + q2a.w*wmE[3]
                               + q2b.x*wmE[4] + q2b.y*wmE[5] + q2b.z*wmE[6] + q2b.w*wmE[7];
            float z3 = a3 + v3 + q3a.x*wmE[0] + q3a.y*wmE[1] + q3a.z*wmE[2] + q3a.w*wmE[3]
                               + q3b.x*wmE[4] + q3b.y*wmE[5] + q3b.z*wmE[6] + q3b.w*wmE[7];
            zt[(i + 0) * 68 + lane] = fmaxf(z0, 0.f);
            zt[(i + 1) * 68 + lane] = fmaxf(z1, 0.f);
            zt[(i + 2) * 68 + lane] = fmaxf(z2, 0.f);
            zt[(i + 3) * 68 + lane] = fmaxf(z3, 0.f);
        }
        __syncthreads();
        float y[32];
        #pragma unroll
        for (int p = 0; p < 32; ++p) y[p] = hh ? 0.f : bm2[p];
        const float* zrow = &zt[eh * 68 + hh * 32];
        #pragma unroll
        for (int it = 0; it < 8; ++it) {
            float4 z4 = *(const float4*)&zrow[it * 4];
            #pragma unroll
            for (int j = 0; j < 4; ++j) {
                float zv = j == 0 ? z4.x : j == 1 ? z4.y : j == 2 ? z4.z : z4.w;
                int o = hh * 32 + it * 4 + j;
                #pragma unroll
                for (int k = 0; k < 8; ++k) {
                    float4 w = *(const float4*)&Wm2[o * 32 + k * 4];
                    y[k * 4 + 0] += zv * w.x;
                    y[k * 4 + 1] += zv * w.y;
                    y[k * 4 + 2] += zv * w.z;
                    y[k * 4 + 3] += zv * w.w;
                }
            }
        }
        #pragma unroll
        for (int p = 0; p < 32; ++p) y[p] += __shfl_xor(y[p], 32);
        float logit = bias3;
        #pragma unroll
        for (int p = 0; p < 32; ++p) logit += fmaxf(y[p], 0.f) * Wm3[p];
        int e = ebase + eh;
        if (hh == 0 && e < E) out[eid[e]] = logit;
        __syncthreads();
    }
}

extern "C" void kernel_launch(void* const* d_in, const int* in_sizes, int n_in,
                              void* d_out, int out_size, void* d_ws, size_t ws_size,
                              hipStream_t stream) {
    const float* x    = (const float*)d_in[0];
    const int*   ei   = (const int*)d_in[1];
    const float* attr = (const float*)d_in[2];
    const float* W1l  = (const float*)d_in[3];
    const float* W1r  = (const float*)d_in[4];
    const float* b1   = (const float*)d_in[5];
    const float* W2l  = (const float*)d_in[6];
    const float* W2r  = (const float*)d_in[7];
    const float* b2   = (const float*)d_in[8];
    const float* W3l  = (const float*)d_in[9];
    const float* W3r  = (const float*)d_in[10];
    const float* b3   = (const float*)d_in[11];
    const float* Wm1  = (const float*)d_in[12];
    const float* bm1  = (const float*)d_in[13];
    const float* Wm2  = (const float*)d_in[14];
    const float* bm2  = (const float*)d_in[15];
    const float* Wm3  = (const float*)d_in[16];
    const float* bm3  = (const float*)d_in[17];
    float* out = (float*)d_out;

    const int N = in_sizes[0] / 16;
    const int E = in_sizes[1] / 2;

    // Workspace layout
    char* ws = (char*)d_ws;
    size_t off = 0;
    int* cnt    = (int*)(ws + off); off += (size_t)N * 4;
    int* cursor = (int*)(ws + off); off += (size_t)N * 4;
    int* rowptr = (int*)(ws + off); off += (size_t)(N + 1) * 4;
    off = (off + 255) & ~(size_t)255;
    int2* sd    = (int2*)(ws + off); off += (size_t)E * 8;
    int* eid    = (int*)(ws + off);  off += (size_t)E * 4;
    off = (off + 255) & ~(size_t)255;
    float* h1 = (float*)(ws + off); off += (size_t)N * 64 * 4;  // h1, later A
    float* h2 = (float*)(ws + off); off += (size_t)N * 64 * 4;  // h2
    float* mb = (float*)(ws + off); off += (size_t)N * 64 * 4;  // mean scratch
    float* Bf = (float*)(ws + off); off += (size_t)N * 64 * 4;  // B

    hipMemsetAsync(ws, 0, (size_t)N * 8, stream);  // cnt + cursor

    const int TB = 256;
    int ebBlocks  = (E + TB - 1) / TB;
    int nwBlocks  = (N * 64 + TB - 1) / TB;       // one wave per node
    int n32Blocks = (N + 31) / 32;                // 32 nodes per 256-thr block
    int b64Edges  = (E + 63) / 64;                // 64 edges per 64-thr block

    hist_kernel<<<ebBlocks, TB, 0, stream>>>(ei, E, cnt);
    scan_kernel<<<1, 1024, 0, stream>>>(cnt, rowptr, N);
    fill_kernel<<<ebBlocks, TB, 0, stream>>>(ei, E, rowptr, cursor, sd, eid);

    sage16_kernel<<<nwBlocks, TB, 0, stream>>>(x, rowptr, sd, W1l, W1r, b1, h1, N);

    gather_mean_kernel<<<nwBlocks, TB, 0, stream>>>(h1, rowptr, sd, mb, N);
    linear64_kernel<<<n32Blocks, TB, 0, stream>>>(mb, h1, W2l, W2r, b2, h2, N);

    gather_mean_kernel<<<nwBlocks, TB, 0, stream>>>(h2, rowptr, sd, mb, N);
    linear64_ab_kernel<<<n32Blocks, TB, 0, stream>>>(mb, h2, W3l, W3r, b3,
                                                     Wm1, bm1, h1, Bf, N);

    edge_kernel<<<b64Edges, 64, 0, stream>>>(h1, Bf, sd, eid, attr,
                                             Wm1, Wm2, bm2, Wm3, bm3, out, E);
}

// Round 13
// 730.920 us; speedup vs baseline: 3.5270x; 3.5270x over previous
//
#include <hip/hip_runtime.h>

// EdgeClassifierGNN R13. R12's edge kernel spilled: #pragma unroll on
// phase2 (256 float4 weight loads live) + y[32] -> VGPR=256 cap, scratch
// spill = 4GB/dispatch HBM traffic, 2083us. Revert edge to R11's 68-VGPR
// structure (plain it-loop phase2, scalar Wm2 loads); only change: phase1
// gathers 4 edges/iter (8 rows in flight) to attack the latency exposure
// R11 showed at 23.8% occ. Keep R12's improved linear kernels.

__device__ __forceinline__ void fma8(float (&y)[8], float zv,
                                     const float4& a, const float4& b) {
    y[0] += zv * a.x; y[1] += zv * a.y; y[2] += zv * a.z; y[3] += zv * a.w;
    y[4] += zv * b.x; y[5] += zv * b.y; y[6] += zv * b.z; y[7] += zv * b.w;
}

__global__ __launch_bounds__(256) void hist_kernel(const int* __restrict__ ei, int E,
                                                   int* __restrict__ cnt) {
    int e = blockIdx.x * blockDim.x + threadIdx.x;
    if (e < E) atomicAdd(&cnt[ei[E + e]], 1);
}

__global__ __launch_bounds__(1024) void scan_kernel(const int* __restrict__ cnt,
                                                    int* __restrict__ rowptr, int N) {
    __shared__ int sums[1024];
    int t = threadIdx.x;
    int chunk = (N + 1023) >> 10;
    int start = t * chunk;
    int end = min(start + chunk, N);
    int s = 0;
    for (int i = start; i < end; ++i) s += cnt[i];
    sums[t] = s;
    __syncthreads();
    for (int off = 1; off < 1024; off <<= 1) {
        int v = (t >= off) ? sums[t - off] : 0;
        __syncthreads();
        sums[t] += v;
        __syncthreads();
    }
    int run = (t == 0) ? 0 : sums[t - 1];
    if (t == 0) rowptr[0] = 0;
    for (int i = start; i < end; ++i) { run += cnt[i]; rowptr[i + 1] = run; }
}

__global__ __launch_bounds__(256) void fill_kernel(const int* __restrict__ ei, int E,
                                                   const int* __restrict__ rowptr,
                                                   int* __restrict__ cursor,
                                                   int2* __restrict__ sd,
                                                   int* __restrict__ eid) {
    int e = blockIdx.x * blockDim.x + threadIdx.x;
    if (e >= E) return;
    int s = ei[e], d = ei[E + e];
    int p = rowptr[d] + atomicAdd(&cursor[d], 1);
    sd[p] = make_int2(s, d);
    eid[p] = e;
}

// SAGE layer 1: 16 -> 64. One wave per node; 4 groups of 16 lanes gather rows.
__global__ __launch_bounds__(256) void sage16_kernel(
        const float* __restrict__ x, const int* __restrict__ rowptr,
        const int2* __restrict__ sd, const float* __restrict__ Wl,
        const float* __restrict__ Wr, const float* __restrict__ b,
        float* __restrict__ out, int N) {
    int lane = threadIdx.x & 63;
    int wid  = (blockIdx.x * blockDim.x + threadIdx.x) >> 6;
    if (wid >= N) return;
    int f = lane & 15, g = lane >> 4;
    int s0 = rowptr[wid], s1 = rowptr[wid + 1];
    float acc0 = 0.f, acc1 = 0.f;
    int j = s0 + g;
    for (; j + 4 < s1; j += 8) {
        int c0 = sd[j].x, c1 = sd[j + 4].x;
        acc0 += x[(size_t)c0 * 16 + f];
        acc1 += x[(size_t)c1 * 16 + f];
    }
    if (j < s1) acc0 += x[(size_t)sd[j].x * 16 + f];
    float acc = acc0 + acc1;
    acc += __shfl_xor(acc, 16);
    acc += __shfl_xor(acc, 32);
    float inv  = 1.0f / fmaxf((float)(s1 - s0), 1.0f);
    float mean = acc * inv;
    float xi   = x[(size_t)wid * 16 + f];
    float o = b[lane];
    #pragma unroll
    for (int ff = 0; ff < 16; ++ff) {
        float m  = __shfl(mean, ff);
        float xv = __shfl(xi, ff);
        o += m * Wl[ff * 64 + lane];
        o += xv * Wr[ff * 64 + lane];
    }
    out[(size_t)wid * 64 + lane] = fmaxf(o, 0.f);
}

// Mean aggregation 64-wide: one wave per node, 8 rows in flight, zero DS.
__global__ __launch_bounds__(256) void gather_mean_kernel(
        const float* __restrict__ hin, const int* __restrict__ rowptr,
        const int2* __restrict__ sd, float* __restrict__ m, int N) {
    int lane = threadIdx.x & 63;
    int wid  = (blockIdx.x * blockDim.x + threadIdx.x) >> 6;
    if (wid >= N) return;
    int s0 = rowptr[wid], s1 = rowptr[wid + 1];
    float a0 = 0.f, a1 = 0.f, a2 = 0.f, a3 = 0.f;
    float a4 = 0.f, a5 = 0.f, a6 = 0.f, a7 = 0.f;
    int j = s0;
    for (; j + 8 <= s1; j += 8) {
        int c0 = sd[j].x,     c1 = sd[j + 1].x, c2 = sd[j + 2].x, c3 = sd[j + 3].x;
        int c4 = sd[j + 4].x, c5 = sd[j + 5].x, c6 = sd[j + 6].x, c7 = sd[j + 7].x;
        a0 += hin[(size_t)c0 * 64 + lane];
        a1 += hin[(size_t)c1 * 64 + lane];
        a2 += hin[(size_t)c2 * 64 + lane];
        a3 += hin[(size_t)c3 * 64 + lane];
        a4 += hin[(size_t)c4 * 64 + lane];
        a5 += hin[(size_t)c5 * 64 + lane];
        a6 += hin[(size_t)c6 * 64 + lane];
        a7 += hin[(size_t)c7 * 64 + lane];
    }
    for (; j < s1; ++j) a0 += hin[(size_t)sd[j].x * 64 + lane];
    float s = ((a0 + a1) + (a2 + a3)) + ((a4 + a5) + (a6 + a7));
    m[(size_t)wid * 64 + lane] = s / fmaxf((float)(s1 - s0), 1.0f);
}

// out[i] = relu(m[i]@Wl + h[i]@Wr + b). 256 thr = 4 waves, 32 nodes/block.
// lane = (node-oct ns, ch-oct co): y[8] accum; input z broadcast (8 lanes
// same addr); weights as per-co float4 loads (L1-hot).
__global__ __launch_bounds__(256) void linear64_kernel(
        const float* __restrict__ m, const float* __restrict__ h,
        const float* __restrict__ Wl, const float* __restrict__ Wr,
        const float* __restrict__ b, float* __restrict__ out, int N) {
    int lane = threadIdx.x & 63;
    int wv   = threadIdx.x >> 6;
    int ns   = lane >> 3, co = lane & 7;
    int node = blockIdx.x * 32 + wv * 8 + ns;
    int i    = min(node, N - 1);
    float y[8];
    {
        float4 b0 = *(const float4*)&b[co * 8];
        float4 b1 = *(const float4*)&b[co * 8 + 4];
        y[0] = b0.x; y[1] = b0.y; y[2] = b0.z; y[3] = b0.w;
        y[4] = b1.x; y[5] = b1.y; y[6] = b1.z; y[7] = b1.w;
    }
    const float* mrow = &m[(size_t)i * 64];
    const float* hrow = &h[(size_t)i * 64];
    for (int t = 0; t < 16; ++t) {
        float4 z4 = *(const float4*)&mrow[t * 4];
        #pragma unroll
        for (int j = 0; j < 4; ++j) {
            int ff = t * 4 + j;
            float zv = j == 0 ? z4.x : j == 1 ? z4.y : j == 2 ? z4.z : z4.w;
            float4 wa = *(const float4*)&Wl[ff * 64 + co * 8];
            float4 wb = *(const float4*)&Wl[ff * 64 + co * 8 + 4];
            fma8(y, zv, wa, wb);
        }
    }
    for (int t = 0; t < 16; ++t) {
        float4 z4 = *(const float4*)&hrow[t * 4];
        #pragma unroll
        for (int j = 0; j < 4; ++j) {
            int ff = t * 4 + j;
            float zv = j == 0 ? z4.x : j == 1 ? z4.y : j == 2 ? z4.z : z4.w;
            float4 wa = *(const float4*)&Wr[ff * 64 + co * 8];
            float4 wb = *(const float4*)&Wr[ff * 64 + co * 8 + 4];
            fma8(y, zv, wa, wb);
        }
    }
    if (node < N) {
        float4 o0 = make_float4(fmaxf(y[0], 0.f), fmaxf(y[1], 0.f),
                                fmaxf(y[2], 0.f), fmaxf(y[3], 0.f));
        float4 o1 = make_float4(fmaxf(y[4], 0.f), fmaxf(y[5], 0.f),
                                fmaxf(y[6], 0.f), fmaxf(y[7], 0.f));
        *(float4*)&out[(size_t)node * 64 + co * 8]     = o0;
        *(float4*)&out[(size_t)node * 64 + co * 8 + 4] = o1;
    }
}

// Layer-3 linear fused with A/B precompute. Same lane mapping; h3 exchanged
// through a padded per-wave LDS tile (stride 68 -> conflict-free b128).
__global__ __launch_bounds__(256) void linear64_ab_kernel(
        const float* __restrict__ m, const float* __restrict__ h,
        const float* __restrict__ Wl, const float* __restrict__ Wr,
        const float* __restrict__ b, const float* __restrict__ Wm1,
        const float* __restrict__ bm1, float* __restrict__ A,
        float* __restrict__ Bf, int N) {
    __shared__ float xch[4][8 * 68];
    int lane = threadIdx.x & 63;
    int wv   = threadIdx.x >> 6;
    int ns   = lane >> 3, co = lane & 7;
    int node = blockIdx.x * 32 + wv * 8 + ns;
    int i    = min(node, N - 1);
    float y[8];
    {
        float4 b0 = *(const float4*)&b[co * 8];
        float4 b1 = *(const float4*)&b[co * 8 + 4];
        y[0] = b0.x; y[1] = b0.y; y[2] = b0.z; y[3] = b0.w;
        y[4] = b1.x; y[5] = b1.y; y[6] = b1.z; y[7] = b1.w;
    }
    const float* mrow = &m[(size_t)i * 64];
    const float* hrow = &h[(size_t)i * 64];
    for (int t = 0; t < 16; ++t) {
        float4 z4 = *(const float4*)&mrow[t * 4];
        #pragma unroll
        for (int j = 0; j < 4; ++j) {
            int ff = t * 4 + j;
            float zv = j == 0 ? z4.x : j == 1 ? z4.y : j == 2 ? z4.z : z4.w;
            float4 wa = *(const float4*)&Wl[ff * 64 + co * 8];
            float4 wb = *(const float4*)&Wl[ff * 64 + co * 8 + 4];
            fma8(y, zv, wa, wb);
        }
    }
    for (int t = 0; t < 16; ++t) {
        float4 z4 = *(const float4*)&hrow[t * 4];
        #pragma unroll
        for (int j = 0; j < 4; ++j) {
            int ff = t * 4 + j;
            float zv = j == 0 ? z4.x : j == 1 ? z4.y : j == 2 ? z4.z : z4.w;
            float4 wa = *(const float4*)&Wr[ff * 64 + co * 8];
            float4 wb = *(const float4*)&Wr[ff * 64 + co * 8 + 4];
            fma8(y, zv, wa, wb);
        }
    }
    // h3 = relu(y); exchange so each lane can read its node's full h3 row.
    {
        float4 h0 = make_float4(fmaxf(y[0], 0.f), fmaxf(y[1], 0.f),
                                fmaxf(y[2], 0.f), fmaxf(y[3], 0.f));
        float4 h1 = make_float4(fmaxf(y[4], 0.f), fmaxf(y[5], 0.f),
                                fmaxf(y[6], 0.f), fmaxf(y[7], 0.f));
        *(float4*)&xch[wv][ns * 68 + co * 8]     = h0;
        *(float4*)&xch[wv][ns * 68 + co * 8 + 4] = h1;
    }
    __syncthreads();
    float yA[8], yB[8];
    {
        float4 b0 = *(const float4*)&bm1[co * 8];
        float4 b1 = *(const float4*)&bm1[co * 8 + 4];
        yA[0] = b0.x; yA[1] = b0.y; yA[2] = b0.z; yA[3] = b0.w;
        yA[4] = b1.x; yA[5] = b1.y; yA[6] = b1.z; yA[7] = b1.w;
        #pragma unroll
        for (int q = 0; q < 8; ++q) yB[q] = 0.f;
    }
    const float* zrow = &xch[wv][ns * 68];
    for (int t = 0; t < 16; ++t) {
        float4 z4 = *(const float4*)&zrow[t * 4];
        #pragma unroll
        for (int j = 0; j < 4; ++j) {
            int ff = t * 4 + j;
            float zv = j == 0 ? z4.x : j == 1 ? z4.y : j == 2 ? z4.z : z4.w;
            float4 wa = *(const float4*)&Wm1[ff * 64 + co * 8];
            float4 wb = *(const float4*)&Wm1[ff * 64 + co * 8 + 4];
            fma8(yA, zv, wa, wb);
            float4 va = *(const float4*)&Wm1[(64 + ff) * 64 + co * 8];
            float4 vb = *(const float4*)&Wm1[(64 + ff) * 64 + co * 8 + 4];
            fma8(yB, zv, va, vb);
        }
    }
    if (node < N) {
        *(float4*)&A[(size_t)node * 64 + co * 8] =
            make_float4(yA[0], yA[1], yA[2], yA[3]);
        *(float4*)&A[(size_t)node * 64 + co * 8 + 4] =
            make_float4(yA[4], yA[5], yA[6], yA[7]);
        *(float4*)&Bf[(size_t)node * 64 + co * 8] =
            make_float4(yB[0], yB[1], yB[2], yB[3]);
        *(float4*)&Bf[(size_t)node * 64 + co * 8 + 4] =
            make_float4(yB[4], yB[5], yB[6], yB[7]);
    }
}

// Edge MLP (R11 structure, 68 VGPR, NO aggressive unroll in phase2).
// Phase1 (lane=channel, 4-edge unroll for 8 gathered rows in flight):
// z = relu(A[src]+B[dst]+attr[eid]@WmE) -> LDS rows (stride 68).
// Phase2 (lane=edge): y[32] accum via plain it-loop + scalar Wm2 loads,
// logit = relu(y)@Wm3 + bm3, scatter to out[eid].
__global__ __launch_bounds__(64) void edge_kernel(
        const float* __restrict__ A, const float* __restrict__ Bf,
        const int2* __restrict__ sd, const int* __restrict__ eid,
        const float* __restrict__ attr,
        const float* __restrict__ Wm1, const float* __restrict__ Wm2,
        const float* __restrict__ bm2, const float* __restrict__ Wm3,
        const float* __restrict__ bm3, float* __restrict__ out, int E) {
    __shared__ float zt[64 * 68];
    int lane = threadIdx.x;
    int base = blockIdx.x * 64;
    float wmE[8];
    #pragma unroll
    for (int k = 0; k < 8; ++k) wmE[k] = Wm1[(128 + k) * 64 + lane];
    const float4* attr4 = (const float4*)attr;

    for (int i = 0; i < 64; i += 4) {
        int e0 = base + i;
        int ec0 = min(e0,     E - 1), ec1 = min(e0 + 1, E - 1);
        int ec2 = min(e0 + 2, E - 1), ec3 = min(e0 + 3, E - 1);
        int2 p0 = sd[ec0], p1 = sd[ec1], p2 = sd[ec2], p3 = sd[ec3];
        int id0 = eid[ec0], id1 = eid[ec1], id2 = eid[ec2], id3 = eid[ec3];
        float a0 = A[(size_t)p0.x * 64 + lane];
        float a1 = A[(size_t)p1.x * 64 + lane];
        float a2 = A[(size_t)p2.x * 64 + lane];
        float a3 = A[(size_t)p3.x * 64 + lane];
        float v0 = Bf[(size_t)p0.y * 64 + lane];
        float v1 = Bf[(size_t)p1.y * 64 + lane];
        float v2 = Bf[(size_t)p2.y * 64 + lane];
        float v3 = Bf[(size_t)p3.y * 64 + lane];
        float4 q0a = attr4[(size_t)id0 * 2], q0b = attr4[(size_t)id0 * 2 + 1];
        float4 q1a = attr4[(size_t)id1 * 2], q1b = attr4[(size_t)id1 * 2 + 1];
        float4 q2a = attr4[(size_t)id2 * 2], q2b = attr4[(size_t)id2 * 2 + 1];
        float4 q3a = attr4[(size_t)id3 * 2], q3b = attr4[(size_t)id3 * 2 + 1];
        float z0 = a0 + v0 + q0a.x*wmE[0] + q0a.y*wmE[1] + q0a.z*wmE[2] + q0a.w*wmE[3]
                           + q0b.x*wmE[4] + q0b.y*wmE[5] + q0b.z*wmE[6] + q0b.w*wmE[7];
        float z1 = a1 + v1 + q1a.x*wmE[0] + q1a.y*wmE[1] + q1a.z*wmE[2] + q1a.w*wmE[3]
                           + q1b.x*wmE[4] + q1b.y*wmE[5] + q1b.z*wmE[6] + q1b.w*wmE[7];
        float z2 = a2 + v2 + q2a.x*wmE[0] + q2a.y*wmE[1] + q2a.z*wmE[2] + q2a.w*wmE[3]
                           + q2b.x*wmE[4] + q2b.y*wmE[5] + q2b.z*wmE[6] + q2b.w*wmE[7];
        float z3 = a3 + v3 + q3a.x*wmE[0] + q3a.y*wmE[1] + q3a.z*wmE[2] + q3a.w*wmE[3]
                           + q3b.x*wmE[4] + q3b.y*wmE[5] + q3b.z*wmE[6] + q3b.w*wmE[7];
        zt[(i + 0) * 68 + lane] = fmaxf(z0, 0.f);
        zt[(i + 1) * 68 + lane] = fmaxf(z1, 0.f);
        zt[(i + 2) * 68 + lane] = fmaxf(z2, 0.f);
        zt[(i + 3) * 68 + lane] = fmaxf(z3, 0.f);
    }
    __syncthreads();
    // Phase2: one edge per lane, plain loops (keeps VGPR ~70, no spill).
    float y[32];
    #pragma unroll
    for (int p = 0; p < 32; ++p) y[p] = bm2[p];
    const float* zrow = &zt[lane * 68];
    for (int it = 0; it < 16; ++it) {           // NO unroll pragma (R12 lesson)
        float4 z4 = *(const float4*)&zrow[it * 4];
        #pragma unroll
        for (int j = 0; j < 4; ++j) {
            float zv = j == 0 ? z4.x : j == 1 ? z4.y : j == 2 ? z4.z : z4.w;
            int o = it * 4 + j;
            #pragma unroll
            for (int p = 0; p < 32; ++p) y[p] += zv * Wm2[o * 32 + p];
        }
    }
    float logit = bm3[0];
    #pragma unroll
    for (int p = 0; p < 32; ++p) logit += fmaxf(y[p], 0.f) * Wm3[p];
    int e = base + lane;
    if (e < E) out[eid[e]] = logit;
}

extern "C" void kernel_launch(void* const* d_in, const int* in_sizes, int n_in,
                              void* d_out, int out_size, void* d_ws, size_t ws_size,
                              hipStream_t stream) {
    const float* x    = (const float*)d_in[0];
    const int*   ei   = (const int*)d_in[1];
    const float* attr = (const float*)d_in[2];
    const float* W1l  = (const float*)d_in[3];
    const float* W1r  = (const float*)d_in[4];
    const float* b1   = (const float*)d_in[5];
    const float* W2l  = (const float*)d_in[6];
    const float* W2r  = (const float*)d_in[7];
    const float* b2   = (const float*)d_in[8];
    const float* W3l  = (const float*)d_in[9];
    const float* W3r  = (const float*)d_in[10];
    const float* b3   = (const float*)d_in[11];
    const float* Wm1  = (const float*)d_in[12];
    const float* bm1  = (const float*)d_in[13];
    const float* Wm2  = (const float*)d_in[14];
    const float* bm2  = (const float*)d_in[15];
    const float* Wm3  = (const float*)d_in[16];
    const float* bm3  = (const float*)d_in[17];
    float* out = (float*)d_out;

    const int N = in_sizes[0] / 16;
    const int E = in_sizes[1] / 2;

    // Workspace layout
    char* ws = (char*)d_ws;
    size_t off = 0;
    int* cnt    = (int*)(ws + off); off += (size_t)N * 4;
    int* cursor = (int*)(ws + off); off += (size_t)N * 4;
    int* rowptr = (int*)(ws + off); off += (size_t)(N + 1) * 4;
    off = (off + 255) & ~(size_t)255;
    int2* sd    = (int2*)(ws + off); off += (size_t)E * 8;
    int* eid    = (int*)(ws + off);  off += (size_t)E * 4;
    off = (off + 255) & ~(size_t)255;
    float* h1 = (float*)(ws + off); off += (size_t)N * 64 * 4;  // h1, later A
    float* h2 = (float*)(ws + off); off += (size_t)N * 64 * 4;  // h2
    float* mb = (float*)(ws + off); off += (size_t)N * 64 * 4;  // mean scratch
    float* Bf = (float*)(ws + off); off += (size_t)N * 64 * 4;  // B

    hipMemsetAsync(ws, 0, (size_t)N * 8, stream);  // cnt + cursor

    const int TB = 256;
    int ebBlocks  = (E + TB - 1) / TB;
    int nwBlocks  = (N * 64 + TB - 1) / TB;       // one wave per node
    int n32Blocks = (N + 31) / 32;                // 32 nodes per 256-thr block
    int b64Edges  = (E + 63) / 64;                // 64 edges per 64-thr block

    hist_kernel<<<ebBlocks, TB, 0, stream>>>(ei, E, cnt);
    scan_kernel<<<1, 1024, 0, stream>>>(cnt, rowptr, N);
    fill_kernel<<<ebBlocks, TB, 0, stream>>>(ei, E, rowptr, cursor, sd, eid);

    sage16_kernel<<<nwBlocks, TB, 0, stream>>>(x, rowptr, sd, W1l, W1r, b1, h1, N);

    gather_mean_kernel<<<nwBlocks, TB, 0, stream>>>(h1, rowptr, sd, mb, N);
    linear64_kernel<<<n32Blocks, TB, 0, stream>>>(mb, h1, W2l, W2r, b2, h2, N);

    gather_mean_kernel<<<nwBlocks, TB, 0, stream>>>(h2, rowptr, sd, mb, N);
    linear64_ab_kernel<<<n32Blocks, TB, 0, stream>>>(mb, h2, W3l, W3r, b3,
                                                     Wm1, bm1, h1, Bf, N);

    edge_kernel<<<b64Edges, 64, 0, stream>>>(h1, Bf, sd, eid, attr,
                                             Wm1, Wm2, bm2, Wm3, bm3, out, E);
}